// Round 1
// baseline (1925.158 us; speedup 1.0000x reference)
//
#include <hip/hip_runtime.h>
#include <hip/hip_bf16.h>
#include <math.h>

// ============================================================================
// ImprovedTransformerBlock on MI355X.
// Precision plan: pre-gate path (QKV/attn/out-proj/conv) in bf16x2-split MFMA
// GEMMs (fp32-grade, protects top-2 routing); attention core fp32 VALU;
// post-gate (MoE experts, FFN) plain bf16 MFMA.
// ============================================================================

typedef unsigned short UST;
typedef unsigned int uint32;
typedef float f32x4 __attribute__((ext_vector_type(4)));
using s16x8 = __attribute__((ext_vector_type(8))) short;   // 8 bf16 = 4 VGPRs

#define DEV __device__ __forceinline__

DEV UST f2bf(float f) {                       // round-to-nearest-even fp32->bf16
    uint32 u = __float_as_uint(f);
    u += 0x7FFFu + ((u >> 16) & 1u);
    return (UST)(u >> 16);
}
DEV float bf2f(UST h) { return __uint_as_float(((uint32)h) << 16); }
DEV float gelu_f(float x) { return 0.5f * x * (1.0f + erff(x * 0.7071067811865475f)); }

// ---------------------------------------------------------------------------
// LayerNorm -> split bf16 (hi/lo) written into conv-padded row layout:
// row(t) = t + 2 + 4*(t>>12); rows {b*4100+0,1,4098,4099} stay zero (memset).
// ---------------------------------------------------------------------------
__global__ void ln_split_kernel(const float* __restrict__ x,
                                const float* __restrict__ g, const float* __restrict__ b,
                                UST* __restrict__ oh, UST* __restrict__ ol)
{
    const int t = blockIdx.x;
    const int tid = threadIdx.x;
    const float4 v = ((const float4*)(x + (long)t * 1024))[tid];
    float s = v.x + v.y + v.z + v.w;
    float q = v.x * v.x + v.y * v.y + v.z * v.z + v.w * v.w;
    for (int o = 32; o > 0; o >>= 1) { s += __shfl_xor(s, o, 64); q += __shfl_xor(q, o, 64); }
    __shared__ float ss[4], sq[4];
    const int wave = tid >> 6, lane = tid & 63;
    if (lane == 0) { ss[wave] = s; sq[wave] = q; }
    __syncthreads();
    s = ss[0] + ss[1] + ss[2] + ss[3];
    q = sq[0] + sq[1] + sq[2] + sq[3];
    const float mean = s * (1.0f / 1024.0f);
    const float var = q * (1.0f / 1024.0f) - mean * mean;
    const float rstd = 1.0f / sqrtf(var + 1e-5f);
    const long row = (long)t + 2 + 4 * (t >> 12);
    UST* ph = oh + row * 1024 + tid * 4;
    UST* pl = ol + row * 1024 + tid * 4;
    const float4 gg = ((const float4*)g)[tid];
    const float4 bb = ((const float4*)b)[tid];
    float vv[4] = { v.x, v.y, v.z, v.w };
    float gv[4] = { gg.x, gg.y, gg.z, gg.w };
    float bv[4] = { bb.x, bb.y, bb.z, bb.w };
#pragma unroll
    for (int j = 0; j < 4; j++) {
        float f = (vv[j] - mean) * rstd * gv[j] + bv[j];
        UST hi = f2bf(f);
        ph[j] = hi;
        pl[j] = f2bf(f - bf2f(hi));
    }
}

// ---------------------------------------------------------------------------
// Weight prep: dst[n*K+k] = src[k*sr + n*sc] as bf16 hi (+lo if dl != null).
// ---------------------------------------------------------------------------
__global__ void prep_w_kernel(const float* __restrict__ src, UST* __restrict__ dh,
                              UST* __restrict__ dl, int K, long sr, long sc, long total)
{
    long gid = (long)blockIdx.x * 256 + threadIdx.x;
    if (gid >= total) return;
    long n = gid / K, k = gid - n * K;
    float v = src[k * sr + n * sc];
    UST hi = f2bf(v);
    dh[gid] = hi;
    if (dl) dl[gid] = f2bf(v - bf2f(hi));
}

// ---------------------------------------------------------------------------
// GEMM: C[M,N] = A[M,K] * B^T[N,K]  (bf16 inputs, fp32 accum, MFMA 16x16x32)
// 128x128 tile, BK=32, 256 threads (2x2 waves, each 64x64 via 4x4 MFMA tiles).
// SPLIT: A=Ah+Al, B=Bh+Bl -> acc += AhBh + AhBl + AlBh  (fp32-grade).
// A-row remap: arow = m + rb + radd*(m>>12) (LN padded layout / conv shifts).
// EPI 0: Cf = acc (+bias) (+resid), fp32.  EPI 1: Cb = bf16(gelu(acc+bias)).
// ---------------------------------------------------------------------------
template<int EPI, bool SPLIT>
__global__ __launch_bounds__(256)
void gemm_bt_kernel(const UST* __restrict__ Ah, const UST* __restrict__ Al,
                    const UST* __restrict__ Bh, const UST* __restrict__ Bl,
                    const float* __restrict__ bias, const float* __restrict__ resid,
                    float* __restrict__ Cf, UST* __restrict__ Cb,
                    int M, int N, int K, int rb, int radd)
{
    __shared__ UST sA[(SPLIT ? 2 : 1) * 128 * 32];
    __shared__ UST sB[(SPLIT ? 2 : 1) * 128 * 32];
    const int tid = threadIdx.x;
    const int wave = tid >> 6, lane = tid & 63;
    const int wr = wave >> 1, wc = wave & 1;
    const int lm = lane & 15, lq = lane >> 4;
    const long m0 = (long)blockIdx.y * 128, n0 = (long)blockIdx.x * 128;
    const int srow = tid >> 1;
    const int scol = (tid & 1) * 16;
    const long arow = m0 + srow + rb + (long)radd * (int)(m0 >> 12);
    const UST* pAh = Ah + arow * K + scol;
    const UST* pBh = Bh + (n0 + srow) * K + scol;
    const UST* pAl = SPLIT ? (Al + arow * K + scol) : nullptr;
    const UST* pBl = SPLIT ? (Bl + (n0 + srow) * K + scol) : nullptr;
    UST* dA0 = &sA[srow * 32 + scol];
    UST* dB0 = &sB[srow * 32 + scol];

    f32x4 acc[4][4] = {};

    for (int k0 = 0; k0 < K; k0 += 32) {
        *(s16x8*)(dA0)     = *(const s16x8*)(pAh + k0);
        *(s16x8*)(dA0 + 8) = *(const s16x8*)(pAh + k0 + 8);
        *(s16x8*)(dB0)     = *(const s16x8*)(pBh + k0);
        *(s16x8*)(dB0 + 8) = *(const s16x8*)(pBh + k0 + 8);
        if (SPLIT) {
            *(s16x8*)(dA0 + 128 * 32)     = *(const s16x8*)(pAl + k0);
            *(s16x8*)(dA0 + 128 * 32 + 8) = *(const s16x8*)(pAl + k0 + 8);
            *(s16x8*)(dB0 + 128 * 32)     = *(const s16x8*)(pBl + k0);
            *(s16x8*)(dB0 + 128 * 32 + 8) = *(const s16x8*)(pBl + k0 + 8);
        }
        __syncthreads();
        s16x8 ah[4], bh[4];
#pragma unroll
        for (int i = 0; i < 4; i++) {
            ah[i] = *(const s16x8*)&sA[(wr * 64 + i * 16 + lm) * 32 + lq * 8];
            bh[i] = *(const s16x8*)&sB[(wc * 64 + i * 16 + lm) * 32 + lq * 8];
        }
#pragma unroll
        for (int i = 0; i < 4; i++)
#pragma unroll
            for (int j = 0; j < 4; j++)
                acc[i][j] = __builtin_amdgcn_mfma_f32_16x16x32_bf16(ah[i], bh[j], acc[i][j], 0, 0, 0);
        if (SPLIT) {
            s16x8 al[4], bl[4];
#pragma unroll
            for (int i = 0; i < 4; i++) {
                al[i] = *(const s16x8*)&sA[128 * 32 + (wr * 64 + i * 16 + lm) * 32 + lq * 8];
                bl[i] = *(const s16x8*)&sB[128 * 32 + (wc * 64 + i * 16 + lm) * 32 + lq * 8];
            }
#pragma unroll
            for (int i = 0; i < 4; i++)
#pragma unroll
                for (int j = 0; j < 4; j++) {
                    acc[i][j] = __builtin_amdgcn_mfma_f32_16x16x32_bf16(ah[i], bl[j], acc[i][j], 0, 0, 0);
                    acc[i][j] = __builtin_amdgcn_mfma_f32_16x16x32_bf16(al[i], bh[j], acc[i][j], 0, 0, 0);
                }
        }
        __syncthreads();
    }

    // C/D layout (m89/m91-verified): col = lane&15, row = (lane>>4)*4 + reg
#pragma unroll
    for (int i = 0; i < 4; i++) {
#pragma unroll
        for (int j = 0; j < 4; j++) {
#pragma unroll
            for (int r = 0; r < 4; r++) {
                const long grow = m0 + wr * 64 + i * 16 + lq * 4 + r;
                const long gcol = n0 + wc * 64 + j * 16 + lm;
                const long idx = grow * N + gcol;
                float v = acc[i][j][r];
                if (bias) v += bias[gcol];
                if (EPI == 0) {
                    if (resid) v += resid[idx];
                    Cf[idx] = v;
                } else {
                    Cb[idx] = f2bf(gelu_f(v));
                }
            }
        }
    }
}

// ---------------------------------------------------------------------------
// Windowed attention, fp32, two-pass online softmax. One block = (b,win,head),
// thread = one query row. K staged in LDS (64 KB); V read via broadcast loads.
// Output written as bf16 hi/lo pair (feeds split out-proj GEMM).
// ---------------------------------------------------------------------------
__global__ __launch_bounds__(256)
void attn_kernel(const float* __restrict__ qkv, UST* __restrict__ oh, UST* __restrict__ ol)
{
    __shared__ float Ks[256 * 64];   // 64 KB
    const int idx = blockIdx.x;
    const int h = idx & 15, w = (idx >> 4) & 15, b = idx >> 8;
    const long tok0 = (long)b * 4096 + w * 256;
    const int tid = threadIdx.x;
#pragma unroll
    for (int i = 0; i < 16; i++) {
        int flat = i * 1024 + tid * 4;
        int r = flat >> 6, c = flat & 63;
        *(float4*)&Ks[flat] = *(const float4*)(qkv + (tok0 + r) * 3072 + 1024 + h * 64 + c);
    }
    float q[64];
    const float* qp = qkv + (tok0 + tid) * 3072 + h * 64;
#pragma unroll
    for (int d = 0; d < 64; d += 4) {
        float4 t4 = *(const float4*)(qp + d);
        q[d] = t4.x; q[d + 1] = t4.y; q[d + 2] = t4.z; q[d + 3] = t4.w;
    }
    __syncthreads();
    float m = -1e30f, l = 0.0f;
    for (int k = 0; k < 256; k++) {
        float s0 = 0, s1 = 0, s2 = 0, s3 = 0;
        const float* kr = &Ks[k * 64];
#pragma unroll
        for (int d = 0; d < 64; d += 4) {
            s0 += q[d] * kr[d]; s1 += q[d + 1] * kr[d + 1];
            s2 += q[d + 2] * kr[d + 2]; s3 += q[d + 3] * kr[d + 3];
        }
        float s = (s0 + s1 + s2 + s3) * 0.125f;
        float nm = fmaxf(m, s);
        l = l * __expf(m - nm) + __expf(s - nm);
        m = nm;
    }
    float o[64];
#pragma unroll
    for (int d = 0; d < 64; d++) o[d] = 0.0f;
    const float* vbase = qkv + tok0 * 3072 + 2048 + h * 64;
    for (int k = 0; k < 256; k++) {
        float s0 = 0, s1 = 0, s2 = 0, s3 = 0;
        const float* kr = &Ks[k * 64];
#pragma unroll
        for (int d = 0; d < 64; d += 4) {
            s0 += q[d] * kr[d]; s1 += q[d + 1] * kr[d + 1];
            s2 += q[d + 2] * kr[d + 2]; s3 += q[d + 3] * kr[d + 3];
        }
        float wgt = __expf((s0 + s1 + s2 + s3) * 0.125f - m);
        const float* vr = vbase + (long)k * 3072;
#pragma unroll
        for (int d = 0; d < 64; d += 4) {
            float4 v4 = *(const float4*)(vr + d);
            o[d] += wgt * v4.x; o[d + 1] += wgt * v4.y;
            o[d + 2] += wgt * v4.z; o[d + 3] += wgt * v4.w;
        }
    }
    const float inv = 1.0f / l;
    UST* po = oh + (tok0 + tid) * 1024 + h * 64;
    UST* pl2 = ol + (tok0 + tid) * 1024 + h * 64;
#pragma unroll
    for (int d = 0; d < 64; d++) {
        float f = o[d] * inv;
        UST hi = f2bf(f);
        po[d] = hi;
        pl2[d] = f2bf(f - bf2f(hi));
    }
}

// ---------------------------------------------------------------------------
// Gate: logits (hi+lo fp32-grade), softmax, entropy, top-2 -> combine weights.
// One wave per token.
// ---------------------------------------------------------------------------
__global__ void gate_kernel(const UST* __restrict__ lnh, const UST* __restrict__ lnl,
                            const float* __restrict__ gw, const float* __restrict__ gb,
                            float* __restrict__ combine, float* __restrict__ ent_acc)
{
    const int tid = threadIdx.x;
    const int t = blockIdx.x * 4 + (tid >> 6);
    const int lane = tid & 63;
    const long row = (long)t + 2 + 4 * (t >> 12);
    const UST* ph = lnh + row * 1024;
    const UST* pl = lnl + row * 1024;
    float acc[8] = { 0, 0, 0, 0, 0, 0, 0, 0 };
    for (int c = 0; c < 16; c++) {
        int d = c * 64 + lane;
        float xv = bf2f(ph[d]) + bf2f(pl[d]);
        const float* wr = gw + (long)d * 8;
#pragma unroll
        for (int e = 0; e < 8; e++) acc[e] += xv * wr[e];
    }
#pragma unroll
    for (int e = 0; e < 8; e++)
        for (int o = 32; o > 0; o >>= 1) acc[e] += __shfl_xor(acc[e], o, 64);
    if (lane == 0) {
        float lg[8], p[8];
        float mx = -1e30f;
        for (int e = 0; e < 8; e++) { lg[e] = acc[e] + gb[e]; mx = fmaxf(mx, lg[e]); }
        float sum = 0;
        for (int e = 0; e < 8; e++) { p[e] = expf(lg[e] - mx); sum += p[e]; }
        float inv = 1.0f / sum;
        float ent = 0;
        for (int e = 0; e < 8; e++) { p[e] *= inv; ent -= p[e] * logf(p[e] + 1e-10f); }
        int i1 = 0; float v1 = -1e30f;
        for (int e = 0; e < 8; e++) if (p[e] > v1) { v1 = p[e]; i1 = e; }
        int i2 = 0; float v2 = -1e30f;
        for (int e = 0; e < 8; e++) if (e != i1 && p[e] > v2) { v2 = p[e]; i2 = e; }
        float inv2 = 1.0f / (v1 + v2);
        float cw[8] = { 0, 0, 0, 0, 0, 0, 0, 0 };
        cw[i1] = v1 * inv2; cw[i2] = v2 * inv2;
        float* co = combine + (long)t * 8;
        for (int e = 0; e < 8; e++) co[e] = cw[e];
        atomicAdd(ent_acc, ent);
    }
}

// out[t,f] += sum_j combine[t, half*4+j] * y[t, j*1024+f]
__global__ void moe_combine_kernel(const UST* __restrict__ y, const float* __restrict__ combine,
                                   float* __restrict__ out, int halfsel)
{
    const long gid = (long)blockIdx.x * 256 + threadIdx.x;
    const int t = (int)(gid >> 10), f = (int)(gid & 1023);
    const float* cw = combine + (long)t * 8 + halfsel * 4;
    const UST* yp = y + (long)t * 4096 + f;
    float s = cw[0] * bf2f(yp[0]) + cw[1] * bf2f(yp[1024])
            + cw[2] * bf2f(yp[2048]) + cw[3] * bf2f(yp[3072]);
    out[gid] += s;
}

__global__ void f32_to_bf16_kernel(const float* __restrict__ in, UST* __restrict__ out)
{
    long gid = ((long)blockIdx.x * 256 + threadIdx.x) * 4;
    float4 v = *(const float4*)(in + gid);
    out[gid] = f2bf(v.x); out[gid + 1] = f2bf(v.y);
    out[gid + 2] = f2bf(v.z); out[gid + 3] = f2bf(v.w);
}

__global__ void ent_final_kernel(const float* __restrict__ acc, float* __restrict__ out)
{
    out[0] = 0.1f * acc[0] * (1.0f / 8192.0f);
}

// ===========================================================================
extern "C" void kernel_launch(void* const* d_in, const int* in_sizes, int n_in,
                              void* d_out_, int out_size, void* d_ws, size_t ws_size,
                              hipStream_t stream)
{
    const float* x      = (const float*)d_in[0];
    const float* ln1_g  = (const float*)d_in[1];
    const float* ln1_b  = (const float*)d_in[2];
    const float* qkv_w  = (const float*)d_in[3];
    const float* qkv_b  = (const float*)d_in[4];
    const float* ao_w   = (const float*)d_in[5];
    const float* ao_b   = (const float*)d_in[6];
    const float* ln2_g  = (const float*)d_in[7];
    const float* ln2_b  = (const float*)d_in[8];
    const float* conv_w = (const float*)d_in[9];
    const float* conv_b = (const float*)d_in[10];
    const float* ln3_g  = (const float*)d_in[11];
    const float* ln3_b  = (const float*)d_in[12];
    const float* gate_w = (const float*)d_in[13];
    const float* gate_b = (const float*)d_in[14];
    const float* exp_w  = (const float*)d_in[15];
    const float* exp_b  = (const float*)d_in[16];
    const float* ff_w1  = (const float*)d_in[17];
    const float* ff_b1  = (const float*)d_in[18];
    const float* ff_w2  = (const float*)d_in[19];
    const float* ff_b2  = (const float*)d_in[20];
    float* out = (float*)d_out_;

    char* ws = (char*)d_ws;
    size_t off = 0;
    auto alloc = [&](size_t bytes) -> char* {
        char* p = ws + off;
        off += (bytes + 255) & ~(size_t)255;
        return p;
    };
    UST* qkvWh = (UST*)alloc(3072 * 1024 * 2);
    UST* qkvWl = (UST*)alloc(3072 * 1024 * 2);
    UST* aoWh  = (UST*)alloc(1024 * 1024 * 2);
    UST* aoWl  = (UST*)alloc(1024 * 1024 * 2);
    UST* convWh[3], *convWl[3];
    for (int k = 0; k < 3; k++) { convWh[k] = (UST*)alloc(1024 * 1024 * 2); }
    for (int k = 0; k < 3; k++) { convWl[k] = (UST*)alloc(1024 * 1024 * 2); }
    UST* expW  = (UST*)alloc(8192L * 1024 * 2);
    UST* ff1W  = (UST*)alloc(4096L * 1024 * 2);
    UST* ff2W  = (UST*)alloc(4096L * 1024 * 2);
    const size_t LN_BYTES = 8200L * 1024 * 2;
    UST* LNh = (UST*)alloc(LN_BYTES);
    UST* LNl = (UST*)alloc(LN_BYTES);
    float* combine = (float*)alloc(8192 * 8 * 4);
    float* entacc  = (float*)alloc(256);
    char*  BIG = alloc(8192L * 3072 * 4);     // qkv fp32; later y bf16 / h1 bf16
    UST* OH = (UST*)alloc(8192L * 1024 * 2);  // attn out hi; later x3 bf16
    UST* OL = (UST*)alloc(8192L * 1024 * 2);
    if (off > ws_size) return;  // ws too small -> deliberate clean fail

    float* qkvf = (float*)BIG;
    UST* ybuf = (UST*)BIG;
    UST* h1   = (UST*)BIG;
    UST* x3h  = OH;

    // ---- weight prep (every call; ws is re-poisoned) ----
    auto nb = [](long n) { return (unsigned)((n + 255) / 256); };
    prep_w_kernel<<<nb(3072L * 1024), 256, 0, stream>>>(qkv_w, qkvWh, qkvWl, 1024, 3072, 1, 3072L * 1024);
    prep_w_kernel<<<nb(1024L * 1024), 256, 0, stream>>>(ao_w, aoWh, aoWl, 1024, 1024, 1, 1024L * 1024);
    for (int k = 0; k < 3; k++)
        prep_w_kernel<<<nb(1024L * 1024), 256, 0, stream>>>(conv_w + k, convWh[k], convWl[k], 1024, 3, 3072, 1024L * 1024);
    for (int e = 0; e < 8; e++)
        prep_w_kernel<<<nb(1024L * 1024), 256, 0, stream>>>(exp_w + (long)e * 1048576, expW + (long)e * 1048576,
                                                            nullptr, 1024, 1024, 1, 1024L * 1024);
    prep_w_kernel<<<nb(4096L * 1024), 256, 0, stream>>>(ff_w1, ff1W, nullptr, 1024, 4096, 1, 4096L * 1024);
    prep_w_kernel<<<nb(4096L * 1024), 256, 0, stream>>>(ff_w2, ff2W, nullptr, 4096, 1024, 1, 4096L * 1024);

    hipMemsetAsync(LNh, 0, LN_BYTES, stream);
    hipMemsetAsync(LNl, 0, LN_BYTES, stream);
    hipMemsetAsync(entacc, 0, 4, stream);

    // ---- attention block ----
    ln_split_kernel<<<8192, 256, 0, stream>>>(x, ln1_g, ln1_b, LNh, LNl);
    gemm_bt_kernel<0, true><<<dim3(24, 64), 256, 0, stream>>>(LNh, LNl, qkvWh, qkvWl, qkv_b, nullptr,
                                                              qkvf, nullptr, 8192, 3072, 1024, 2, 4);
    attn_kernel<<<512, 256, 0, stream>>>(qkvf, OH, OL);
    gemm_bt_kernel<0, true><<<dim3(8, 64), 256, 0, stream>>>(OH, OL, aoWh, aoWl, ao_b, x,
                                                             out, nullptr, 8192, 1024, 1024, 0, 0);
    // ---- dilated conv block (3 shifted GEMMs, in-place accumulate) ----
    ln_split_kernel<<<8192, 256, 0, stream>>>(out, ln2_g, ln2_b, LNh, LNl);
    for (int k = 0; k < 3; k++)
        gemm_bt_kernel<0, true><<<dim3(8, 64), 256, 0, stream>>>(LNh, LNl, convWh[k], convWl[k],
                                                                 (k == 0) ? conv_b : nullptr, out,
                                                                 out, nullptr, 8192, 1024, 1024, 2 * k, 4);
    // ---- MoE ----
    ln_split_kernel<<<8192, 256, 0, stream>>>(out, ln3_g, ln3_b, LNh, LNl);
    gate_kernel<<<2048, 256, 0, stream>>>(LNh, LNl, gate_w, gate_b, combine, entacc);
    ent_final_kernel<<<1, 1, 0, stream>>>(entacc, out + 8388608);
    for (int hh = 0; hh < 2; hh++) {
        gemm_bt_kernel<1, false><<<dim3(32, 64), 256, 0, stream>>>(LNh, nullptr, expW + (long)hh * 4096 * 1024,
                                                                   nullptr, exp_b + hh * 4096, nullptr,
                                                                   nullptr, ybuf, 8192, 4096, 1024, 2, 4);
        moe_combine_kernel<<<32768, 256, 0, stream>>>(ybuf, combine, out, hh);
    }
    // ---- FFN ----
    f32_to_bf16_kernel<<<8192, 256, 0, stream>>>(out, x3h);
    gemm_bt_kernel<1, false><<<dim3(32, 64), 256, 0, stream>>>(x3h, nullptr, ff1W, nullptr, ff_b1, nullptr,
                                                               nullptr, h1, 8192, 4096, 1024, 0, 0);
    gemm_bt_kernel<0, false><<<dim3(8, 64), 256, 0, stream>>>(h1, nullptr, ff2W, nullptr, ff_b2, out,
                                                              out, nullptr, 8192, 1024, 4096, 0, 0);
}

// Round 2
// 1845.129 us; speedup vs baseline: 1.0434x; 1.0434x over previous
//
#include <hip/hip_runtime.h>
#include <hip/hip_bf16.h>
#include <math.h>

// ============================================================================
// ImprovedTransformerBlock on MI355X.  R2: global_load_lds(16B) GEMM staging,
// one-pass online-softmax attention, coalesced tiled-transpose weight prep.
// Precision plan unchanged: pre-gate path in bf16x2-split MFMA (fp32-grade),
// attention core fp32 VALU, post-gate plain bf16 MFMA.
// ============================================================================

typedef unsigned short UST;
typedef unsigned int uint32;
typedef float f32x4 __attribute__((ext_vector_type(4)));
using s16x8 = __attribute__((ext_vector_type(8))) short;   // 8 bf16 = 4 VGPRs

#define DEV __device__ __forceinline__

// async global->LDS, 16 bytes/lane; lds ptr must be wave-uniform (lane lands
// at base + lane*16) [m97/m104]
#define GLL(g, l) __builtin_amdgcn_global_load_lds( \
    (const __attribute__((address_space(1))) unsigned int*)(g), \
    (__attribute__((address_space(3))) unsigned int*)(l), 16, 0, 0)

DEV UST f2bf(float f) {                       // round-to-nearest-even fp32->bf16
    uint32 u = __float_as_uint(f);
    u += 0x7FFFu + ((u >> 16) & 1u);
    return (UST)(u >> 16);
}
DEV float bf2f(UST h) { return __uint_as_float(((uint32)h) << 16); }
DEV float gelu_f(float x) { return 0.5f * x * (1.0f + erff(x * 0.7071067811865475f)); }

// ---------------------------------------------------------------------------
// LayerNorm -> split bf16 (hi/lo) written into conv-padded row layout:
// row(t) = t + 2 + 4*(t>>12); rows {b*4100+0,1,4098,4099} stay zero (memset).
// ---------------------------------------------------------------------------
__global__ void ln_split_kernel(const float* __restrict__ x,
                                const float* __restrict__ g, const float* __restrict__ b,
                                UST* __restrict__ oh, UST* __restrict__ ol)
{
    const int t = blockIdx.x;
    const int tid = threadIdx.x;
    const float4 v = ((const float4*)(x + (long)t * 1024))[tid];
    float s = v.x + v.y + v.z + v.w;
    float q = v.x * v.x + v.y * v.y + v.z * v.z + v.w * v.w;
    for (int o = 32; o > 0; o >>= 1) { s += __shfl_xor(s, o, 64); q += __shfl_xor(q, o, 64); }
    __shared__ float ss[4], sq[4];
    const int wave = tid >> 6, lane = tid & 63;
    if (lane == 0) { ss[wave] = s; sq[wave] = q; }
    __syncthreads();
    s = ss[0] + ss[1] + ss[2] + ss[3];
    q = sq[0] + sq[1] + sq[2] + sq[3];
    const float mean = s * (1.0f / 1024.0f);
    const float var = q * (1.0f / 1024.0f) - mean * mean;
    const float rstd = 1.0f / sqrtf(var + 1e-5f);
    const long row = (long)t + 2 + 4 * (t >> 12);
    UST* ph = oh + row * 1024 + tid * 4;
    UST* pl = ol + row * 1024 + tid * 4;
    const float4 gg = ((const float4*)g)[tid];
    const float4 bb = ((const float4*)b)[tid];
    float vv[4] = { v.x, v.y, v.z, v.w };
    float gv[4] = { gg.x, gg.y, gg.z, gg.w };
    float bv[4] = { bb.x, bb.y, bb.z, bb.w };
#pragma unroll
    for (int j = 0; j < 4; j++) {
        float f = (vv[j] - mean) * rstd * gv[j] + bv[j];
        UST hi = f2bf(f);
        ph[j] = hi;
        pl[j] = f2bf(f - bf2f(hi));
    }
}

// ---------------------------------------------------------------------------
// Coalesced transpose prep: dst[n*K+k] = src[k*N+n], bf16 hi (+lo).
// Tile 32(k) x 64(n) via LDS. Grid (N/64, K/32), 256 threads.
// ---------------------------------------------------------------------------
__global__ void prep_t_kernel(const float* __restrict__ src, UST* __restrict__ dh,
                              UST* __restrict__ dl, int N, int K)
{
    __shared__ float tile[32][65];
    const int k0 = blockIdx.y * 32, n0 = blockIdx.x * 64;
    const int t = threadIdx.x;
    const int nn = t & 63, kk = t >> 6;
#pragma unroll
    for (int i = 0; i < 8; i++)
        tile[kk + i * 4][nn] = src[(long)(k0 + kk + i * 4) * N + n0 + nn];
    __syncthreads();
    const int kw = (t & 7) * 4;
#pragma unroll
    for (int pass = 0; pass < 2; pass++) {
        const int nw = (t >> 3) + pass * 32;
        UST hv[4], lv[4];
#pragma unroll
        for (int j = 0; j < 4; j++) {
            float v = tile[kw + j][nw];
            hv[j] = f2bf(v);
            lv[j] = f2bf(v - bf2f(hv[j]));
        }
        UST* bh = dh + (long)(n0 + nw) * K + k0 + kw;
        *(ushort4*)bh = make_ushort4(hv[0], hv[1], hv[2], hv[3]);
        if (dl) {
            UST* bl = dl + (long)(n0 + nw) * K + k0 + kw;
            *(ushort4*)bl = make_ushort4(lv[0], lv[1], lv[2], lv[3]);
        }
    }
}

// Generic (conv taps): dst[n*K+k] = src[k*sr + n*sc]; stride-3 reads, coalesced writes
__global__ void prep_w_kernel(const float* __restrict__ src, UST* __restrict__ dh,
                              UST* __restrict__ dl, int K, long sr, long sc, long total)
{
    long gid = (long)blockIdx.x * 256 + threadIdx.x;
    if (gid >= total) return;
    long n = gid / K, k = gid - n * K;
    float v = src[k * sr + n * sc];
    UST hi = f2bf(v);
    dh[gid] = hi;
    if (dl) dl[gid] = f2bf(v - bf2f(hi));
}

// ---------------------------------------------------------------------------
// GEMM: C[M,N] = A[M,K] * B^T[N,K]  (bf16, fp32 accum, MFMA 16x16x32)
// 128x128 tile, BK=32, 256 threads. Staging via global_load_lds width=16:
// wave wv stages rows [wv*32, wv*32+32) of each 128x32 tile (2 instrs, each
// 64 lanes x 16B = 1KB -> 16 rows). LDS layout row-major [128][32], same as
// fragment reads expect. SPLIT: 3-product bf16x2 (fp32-grade).
// ---------------------------------------------------------------------------
template<int EPI, bool SPLIT>
__global__ __launch_bounds__(256)
void gemm_bt_kernel(const UST* __restrict__ Ah, const UST* __restrict__ Al,
                    const UST* __restrict__ Bh, const UST* __restrict__ Bl,
                    const float* __restrict__ bias, const float* __restrict__ resid,
                    float* __restrict__ Cf, UST* __restrict__ Cb,
                    int M, int N, int K, int rb, int radd)
{
    __shared__ UST sA[(SPLIT ? 2 : 1) * 128 * 32];
    __shared__ UST sB[(SPLIT ? 2 : 1) * 128 * 32];
    const int tid = threadIdx.x;
    const int lane = tid & 63;
    const int wv = __builtin_amdgcn_readfirstlane(tid >> 6);
    const int wr = wv >> 1, wc = wv & 1;
    const int lm = lane & 15, lq = lane >> 4;
    const long m0 = (long)blockIdx.y * 128, n0 = (long)blockIdx.x * 128;

    // staging geometry: lane covers (row = band + lane>>2, col = (lane&3)*8)
    const int lr = lane >> 2, lc = (lane & 3) * 8;
    const int rA0 = wv * 32 + lr, rA1 = wv * 32 + 16 + lr;
    const long mtop = m0 >> 12;              // tiles never straddle 4096 rows
    const UST* gA0 = Ah + (m0 + rA0 + rb + (long)radd * mtop) * K + lc;
    const UST* gA1 = Ah + (m0 + rA1 + rb + (long)radd * mtop) * K + lc;
    const UST* gB0 = Bh + (n0 + rA0) * K + lc;
    const UST* gB1 = Bh + (n0 + rA1) * K + lc;
    const UST* gA0l = SPLIT ? (Al + (m0 + rA0 + rb + (long)radd * mtop) * K + lc) : nullptr;
    const UST* gA1l = SPLIT ? (Al + (m0 + rA1 + rb + (long)radd * mtop) * K + lc) : nullptr;
    const UST* gB0l = SPLIT ? (Bl + (n0 + rA0) * K + lc) : nullptr;
    const UST* gB1l = SPLIT ? (Bl + (n0 + rA1) * K + lc) : nullptr;
    UST* lA0 = &sA[wv * 1024];               // wave-uniform LDS bases
    UST* lA1 = &sA[wv * 1024 + 512];
    UST* lB0 = &sB[wv * 1024];
    UST* lB1 = &sB[wv * 1024 + 512];

    f32x4 acc[4][4] = {};

    for (int k0 = 0; k0 < K; k0 += 32) {
        GLL(gA0 + k0, lA0); GLL(gA1 + k0, lA1);
        GLL(gB0 + k0, lB0); GLL(gB1 + k0, lB1);
        if (SPLIT) {
            GLL(gA0l + k0, lA0 + 4096); GLL(gA1l + k0, lA1 + 4096);
            GLL(gB0l + k0, lB0 + 4096); GLL(gB1l + k0, lB1 + 4096);
        }
        __syncthreads();
        s16x8 ah[4], bh[4];
#pragma unroll
        for (int i = 0; i < 4; i++) {
            ah[i] = *(const s16x8*)&sA[(wr * 64 + i * 16 + lm) * 32 + lq * 8];
            bh[i] = *(const s16x8*)&sB[(wc * 64 + i * 16 + lm) * 32 + lq * 8];
        }
#pragma unroll
        for (int i = 0; i < 4; i++)
#pragma unroll
            for (int j = 0; j < 4; j++)
                acc[i][j] = __builtin_amdgcn_mfma_f32_16x16x32_bf16(ah[i], bh[j], acc[i][j], 0, 0, 0);
        if (SPLIT) {
            s16x8 al[4], bl[4];
#pragma unroll
            for (int i = 0; i < 4; i++) {
                al[i] = *(const s16x8*)&sA[4096 + (wr * 64 + i * 16 + lm) * 32 + lq * 8];
                bl[i] = *(const s16x8*)&sB[4096 + (wc * 64 + i * 16 + lm) * 32 + lq * 8];
            }
#pragma unroll
            for (int i = 0; i < 4; i++)
#pragma unroll
                for (int j = 0; j < 4; j++) {
                    acc[i][j] = __builtin_amdgcn_mfma_f32_16x16x32_bf16(ah[i], bl[j], acc[i][j], 0, 0, 0);
                    acc[i][j] = __builtin_amdgcn_mfma_f32_16x16x32_bf16(al[i], bh[j], acc[i][j], 0, 0, 0);
                }
        }
        __syncthreads();
    }

    // C/D layout (m89/m91-verified): col = lane&15, row = (lane>>4)*4 + reg
#pragma unroll
    for (int i = 0; i < 4; i++) {
#pragma unroll
        for (int j = 0; j < 4; j++) {
#pragma unroll
            for (int r = 0; r < 4; r++) {
                const long grow = m0 + wr * 64 + i * 16 + lq * 4 + r;
                const long gcol = n0 + wc * 64 + j * 16 + lm;
                const long idx = grow * N + gcol;
                float v = acc[i][j][r];
                if (bias) v += bias[gcol];
                if (EPI == 0) {
                    if (resid) v += resid[idx];
                    Cf[idx] = v;
                } else {
                    Cb[idx] = f2bf(gelu_f(v));
                }
            }
        }
    }
}

// ---------------------------------------------------------------------------
// Windowed attention, fp32, ONE-pass online softmax. Block = (b,win,head),
// thread = one query row. K staged in LDS; V broadcast loads; O in registers
// with lazy rescale. Output bf16 hi/lo (feeds split out-proj GEMM).
// ---------------------------------------------------------------------------
__global__ __launch_bounds__(256)
void attn_kernel(const float* __restrict__ qkv, UST* __restrict__ oh, UST* __restrict__ ol)
{
    __shared__ float Ks[256 * 64];   // 64 KB
    const int idx = blockIdx.x;
    const int h = idx & 15, w = (idx >> 4) & 15, b = idx >> 8;
    const long tok0 = (long)b * 4096 + w * 256;
    const int tid = threadIdx.x;
#pragma unroll
    for (int i = 0; i < 16; i++) {
        int flat = i * 1024 + tid * 4;
        int r = flat >> 6, c = flat & 63;
        *(float4*)&Ks[flat] = *(const float4*)(qkv + (tok0 + r) * 3072 + 1024 + h * 64 + c);
    }
    float q[64];
    const float* qp = qkv + (tok0 + tid) * 3072 + h * 64;
#pragma unroll
    for (int d = 0; d < 64; d += 4) {
        float4 t4 = *(const float4*)(qp + d);
        q[d] = t4.x; q[d + 1] = t4.y; q[d + 2] = t4.z; q[d + 3] = t4.w;
    }
    __syncthreads();
    float m = -1e30f, l = 0.0f;
    float o[64];
#pragma unroll
    for (int d = 0; d < 64; d++) o[d] = 0.0f;
    const float* vbase = qkv + tok0 * 3072 + 2048 + h * 64;
    for (int k = 0; k < 256; k++) {
        float s0 = 0, s1 = 0, s2 = 0, s3 = 0;
        const float* kr = &Ks[k * 64];
#pragma unroll
        for (int d = 0; d < 64; d += 4) {
            s0 += q[d] * kr[d]; s1 += q[d + 1] * kr[d + 1];
            s2 += q[d + 2] * kr[d + 2]; s3 += q[d + 3] * kr[d + 3];
        }
        const float s = (s0 + s1 + s2 + s3) * 0.125f;
        const float nm = fmaxf(m, s);
        const float sc = __expf(m - nm);      // == 1.0f unless max updated
        const float wgt = __expf(s - nm);
        l = l * sc + wgt;
        m = nm;
        if (sc != 1.0f) {
#pragma unroll
            for (int d = 0; d < 64; d++) o[d] *= sc;
        }
        const float* vr = vbase + (long)k * 3072;
#pragma unroll
        for (int d = 0; d < 64; d += 4) {
            float4 v4 = *(const float4*)(vr + d);
            o[d] += wgt * v4.x; o[d + 1] += wgt * v4.y;
            o[d + 2] += wgt * v4.z; o[d + 3] += wgt * v4.w;
        }
    }
    const float inv = 1.0f / l;
    UST* po = oh + (tok0 + tid) * 1024 + h * 64;
    UST* pl2 = ol + (tok0 + tid) * 1024 + h * 64;
#pragma unroll
    for (int d = 0; d < 64; d += 4) {
        UST hv[4], lv[4];
#pragma unroll
        for (int j = 0; j < 4; j++) {
            float f = o[d + j] * inv;
            hv[j] = f2bf(f);
            lv[j] = f2bf(f - bf2f(hv[j]));
        }
        *(ushort4*)(po + d) = make_ushort4(hv[0], hv[1], hv[2], hv[3]);
        *(ushort4*)(pl2 + d) = make_ushort4(lv[0], lv[1], lv[2], lv[3]);
    }
}

// ---------------------------------------------------------------------------
// Gate: logits (hi+lo fp32-grade), softmax, entropy, top-2 -> combine weights.
// ---------------------------------------------------------------------------
__global__ void gate_kernel(const UST* __restrict__ lnh, const UST* __restrict__ lnl,
                            const float* __restrict__ gw, const float* __restrict__ gb,
                            float* __restrict__ combine, float* __restrict__ ent_acc)
{
    const int tid = threadIdx.x;
    const int t = blockIdx.x * 4 + (tid >> 6);
    const int lane = tid & 63;
    const long row = (long)t + 2 + 4 * (t >> 12);
    const UST* ph = lnh + row * 1024;
    const UST* pl = lnl + row * 1024;
    float acc[8] = { 0, 0, 0, 0, 0, 0, 0, 0 };
    for (int c = 0; c < 16; c++) {
        int d = c * 64 + lane;
        float xv = bf2f(ph[d]) + bf2f(pl[d]);
        const float* wr = gw + (long)d * 8;
#pragma unroll
        for (int e = 0; e < 8; e++) acc[e] += xv * wr[e];
    }
#pragma unroll
    for (int e = 0; e < 8; e++)
        for (int o = 32; o > 0; o >>= 1) acc[e] += __shfl_xor(acc[e], o, 64);
    if (lane == 0) {
        float lg[8], p[8];
        float mx = -1e30f;
        for (int e = 0; e < 8; e++) { lg[e] = acc[e] + gb[e]; mx = fmaxf(mx, lg[e]); }
        float sum = 0;
        for (int e = 0; e < 8; e++) { p[e] = expf(lg[e] - mx); sum += p[e]; }
        float inv = 1.0f / sum;
        float ent = 0;
        for (int e = 0; e < 8; e++) { p[e] *= inv; ent -= p[e] * logf(p[e] + 1e-10f); }
        int i1 = 0; float v1 = -1e30f;
        for (int e = 0; e < 8; e++) if (p[e] > v1) { v1 = p[e]; i1 = e; }
        int i2 = 0; float v2 = -1e30f;
        for (int e = 0; e < 8; e++) if (e != i1 && p[e] > v2) { v2 = p[e]; i2 = e; }
        float inv2 = 1.0f / (v1 + v2);
        float cw[8] = { 0, 0, 0, 0, 0, 0, 0, 0 };
        cw[i1] = v1 * inv2; cw[i2] = v2 * inv2;
        float* co = combine + (long)t * 8;
        for (int e = 0; e < 8; e++) co[e] = cw[e];
        atomicAdd(ent_acc, ent);
    }
}

// out[t,f] += sum_j combine[t, half*4+j] * y[t, j*1024+f]
__global__ void moe_combine_kernel(const UST* __restrict__ y, const float* __restrict__ combine,
                                   float* __restrict__ out, int halfsel)
{
    const long gid = (long)blockIdx.x * 256 + threadIdx.x;
    const int t = (int)(gid >> 10), f = (int)(gid & 1023);
    const float* cw = combine + (long)t * 8 + halfsel * 4;
    const UST* yp = y + (long)t * 4096 + f;
    float s = cw[0] * bf2f(yp[0]) + cw[1] * bf2f(yp[1024])
            + cw[2] * bf2f(yp[2048]) + cw[3] * bf2f(yp[3072]);
    out[gid] += s;
}

__global__ void f32_to_bf16_kernel(const float* __restrict__ in, UST* __restrict__ out)
{
    long gid = ((long)blockIdx.x * 256 + threadIdx.x) * 4;
    float4 v = *(const float4*)(in + gid);
    out[gid] = f2bf(v.x); out[gid + 1] = f2bf(v.y);
    out[gid + 2] = f2bf(v.z); out[gid + 3] = f2bf(v.w);
}

__global__ void ent_final_kernel(const float* __restrict__ acc, float* __restrict__ out)
{
    out[0] = 0.1f * acc[0] * (1.0f / 8192.0f);
}

// ===========================================================================
extern "C" void kernel_launch(void* const* d_in, const int* in_sizes, int n_in,
                              void* d_out_, int out_size, void* d_ws, size_t ws_size,
                              hipStream_t stream)
{
    const float* x      = (const float*)d_in[0];
    const float* ln1_g  = (const float*)d_in[1];
    const float* ln1_b  = (const float*)d_in[2];
    const float* qkv_w  = (const float*)d_in[3];
    const float* qkv_b  = (const float*)d_in[4];
    const float* ao_w   = (const float*)d_in[5];
    const float* ao_b   = (const float*)d_in[6];
    const float* ln2_g  = (const float*)d_in[7];
    const float* ln2_b  = (const float*)d_in[8];
    const float* conv_w = (const float*)d_in[9];
    const float* conv_b = (const float*)d_in[10];
    const float* ln3_g  = (const float*)d_in[11];
    const float* ln3_b  = (const float*)d_in[12];
    const float* gate_w = (const float*)d_in[13];
    const float* gate_b = (const float*)d_in[14];
    const float* exp_w  = (const float*)d_in[15];
    const float* exp_b  = (const float*)d_in[16];
    const float* ff_w1  = (const float*)d_in[17];
    const float* ff_b1  = (const float*)d_in[18];
    const float* ff_w2  = (const float*)d_in[19];
    const float* ff_b2  = (const float*)d_in[20];
    float* out = (float*)d_out_;

    char* ws = (char*)d_ws;
    size_t off = 0;
    auto alloc = [&](size_t bytes) -> char* {
        char* p = ws + off;
        off += (bytes + 255) & ~(size_t)255;
        return p;
    };
    UST* qkvWh = (UST*)alloc(3072 * 1024 * 2);
    UST* qkvWl = (UST*)alloc(3072 * 1024 * 2);
    UST* aoWh  = (UST*)alloc(1024 * 1024 * 2);
    UST* aoWl  = (UST*)alloc(1024 * 1024 * 2);
    UST* convWh[3], *convWl[3];
    for (int k = 0; k < 3; k++) { convWh[k] = (UST*)alloc(1024 * 1024 * 2); }
    for (int k = 0; k < 3; k++) { convWl[k] = (UST*)alloc(1024 * 1024 * 2); }
    UST* expW  = (UST*)alloc(8192L * 1024 * 2);
    UST* ff1W  = (UST*)alloc(4096L * 1024 * 2);
    UST* ff2W  = (UST*)alloc(4096L * 1024 * 2);
    const size_t LN_BYTES = 8200L * 1024 * 2;
    UST* LNh = (UST*)alloc(LN_BYTES);
    UST* LNl = (UST*)alloc(LN_BYTES);
    float* combine = (float*)alloc(8192 * 8 * 4);
    float* entacc  = (float*)alloc(256);
    char*  BIG = alloc(8192L * 3072 * 4);     // qkv fp32; later y bf16 / h1 bf16
    UST* OH = (UST*)alloc(8192L * 1024 * 2);  // attn out hi; later x3 bf16
    UST* OL = (UST*)alloc(8192L * 1024 * 2);
    if (off > ws_size) return;  // ws too small -> deliberate clean fail

    float* qkvf = (float*)BIG;
    UST* ybuf = (UST*)BIG;
    UST* h1   = (UST*)BIG;
    UST* x3h  = OH;

    // ---- weight prep (every call; ws is re-poisoned) ----
    auto nb = [](long n) { return (unsigned)((n + 255) / 256); };
    prep_t_kernel<<<dim3(48, 32), 256, 0, stream>>>(qkv_w, qkvWh, qkvWl, 3072, 1024);
    prep_t_kernel<<<dim3(16, 32), 256, 0, stream>>>(ao_w, aoWh, aoWl, 1024, 1024);
    for (int k = 0; k < 3; k++)
        prep_w_kernel<<<nb(1024L * 1024), 256, 0, stream>>>(conv_w + k, convWh[k], convWl[k], 1024, 3, 3072, 1024L * 1024);
    for (int e = 0; e < 8; e++)
        prep_t_kernel<<<dim3(16, 32), 256, 0, stream>>>(exp_w + (long)e * 1048576, expW + (long)e * 1048576,
                                                        nullptr, 1024, 1024);
    prep_t_kernel<<<dim3(64, 32), 256, 0, stream>>>(ff_w1, ff1W, nullptr, 4096, 1024);
    prep_t_kernel<<<dim3(16, 128), 256, 0, stream>>>(ff_w2, ff2W, nullptr, 1024, 4096);

    hipMemsetAsync(LNh, 0, LN_BYTES, stream);
    hipMemsetAsync(LNl, 0, LN_BYTES, stream);
    hipMemsetAsync(entacc, 0, 4, stream);

    // ---- attention block ----
    ln_split_kernel<<<8192, 256, 0, stream>>>(x, ln1_g, ln1_b, LNh, LNl);
    gemm_bt_kernel<0, true><<<dim3(24, 64), 256, 0, stream>>>(LNh, LNl, qkvWh, qkvWl, qkv_b, nullptr,
                                                              qkvf, nullptr, 8192, 3072, 1024, 2, 4);
    attn_kernel<<<512, 256, 0, stream>>>(qkvf, OH, OL);
    gemm_bt_kernel<0, true><<<dim3(8, 64), 256, 0, stream>>>(OH, OL, aoWh, aoWl, ao_b, x,
                                                             out, nullptr, 8192, 1024, 1024, 0, 0);
    // ---- dilated conv block (3 shifted GEMMs, in-place accumulate) ----
    ln_split_kernel<<<8192, 256, 0, stream>>>(out, ln2_g, ln2_b, LNh, LNl);
    for (int k = 0; k < 3; k++)
        gemm_bt_kernel<0, true><<<dim3(8, 64), 256, 0, stream>>>(LNh, LNl, convWh[k], convWl[k],
                                                                 (k == 0) ? conv_b : nullptr, out,
                                                                 out, nullptr, 8192, 1024, 1024, 2 * k, 4);
    // ---- MoE ----
    ln_split_kernel<<<8192, 256, 0, stream>>>(out, ln3_g, ln3_b, LNh, LNl);
    gate_kernel<<<2048, 256, 0, stream>>>(LNh, LNl, gate_w, gate_b, combine, entacc);
    ent_final_kernel<<<1, 1, 0, stream>>>(entacc, out + 8388608);
    for (int hh = 0; hh < 2; hh++) {
        gemm_bt_kernel<1, false><<<dim3(32, 64), 256, 0, stream>>>(LNh, nullptr, expW + (long)hh * 4096 * 1024,
                                                                   nullptr, exp_b + hh * 4096, nullptr,
                                                                   nullptr, ybuf, 8192, 4096, 1024, 2, 4);
        moe_combine_kernel<<<32768, 256, 0, stream>>>(ybuf, combine, out, hh);
    }
    // ---- FFN ----
    f32_to_bf16_kernel<<<8192, 256, 0, stream>>>(out, x3h);
    gemm_bt_kernel<1, false><<<dim3(32, 64), 256, 0, stream>>>(x3h, nullptr, ff1W, nullptr, ff_b1, nullptr,
                                                               nullptr, h1, 8192, 4096, 1024, 0, 0);
    gemm_bt_kernel<0, false><<<dim3(8, 64), 256, 0, stream>>>(h1, nullptr, ff2W, nullptr, ff_b2, out,
                                                              out, nullptr, 8192, 1024, 4096, 0, 0);
}

// Round 4
// 1554.201 us; speedup vs baseline: 1.2387x; 1.1872x over previous
//
#include <hip/hip_runtime.h>
#include <hip/hip_bf16.h>
#include <math.h>

// ============================================================================
// ImprovedTransformerBlock on MI355X.  R3 (resubmit; prior bench was an infra
// failure): MFMA attention (split-bf16, no-max softmax, P via per-wave LDS
// transpose), QKV-GEMM epilogue writes Q/K/Vt split directly (no fp32 qkv
// buffer), conv fused to one K=3072 GEMM, pad-zero kernel instead of full LN
// memsets.
// Precision plan: pre-gate path bf16x2-split MFMA (fp32-grade, protects top-2
// routing); post-gate (experts, FFN) plain bf16 MFMA.
// ============================================================================

typedef unsigned short UST;
typedef unsigned int uint32;
typedef float f32x4 __attribute__((ext_vector_type(4)));
using s16x8 = __attribute__((ext_vector_type(8))) short;   // 8 bf16 = 4 VGPRs

#define DEV __device__ __forceinline__
#define MFMA16 __builtin_amdgcn_mfma_f32_16x16x32_bf16

// async global->LDS, 16 bytes/lane; lds dst is wave-uniform base + lane*16
#define GLL(g, l) __builtin_amdgcn_global_load_lds( \
    (const __attribute__((address_space(1))) unsigned int*)(g), \
    (__attribute__((address_space(3))) unsigned int*)(l), 16, 0, 0)

DEV UST f2bf(float f) {                       // round-to-nearest-even fp32->bf16
    uint32 u = __float_as_uint(f);
    u += 0x7FFFu + ((u >> 16) & 1u);
    return (UST)(u >> 16);
}
DEV float bf2f(UST h) { return __uint_as_float(((uint32)h) << 16); }
DEV float gelu_f(float x) { return 0.5f * x * (1.0f + erff(x * 0.7071067811865475f)); }

// ---------------------------------------------------------------------------
// LayerNorm -> split bf16 (hi/lo), conv-padded row layout: row(t)=t+2+4*(t>>12)
// ---------------------------------------------------------------------------
__global__ void ln_split_kernel(const float* __restrict__ x,
                                const float* __restrict__ g, const float* __restrict__ b,
                                UST* __restrict__ oh, UST* __restrict__ ol)
{
    const int t = blockIdx.x;
    const int tid = threadIdx.x;
    const float4 v = ((const float4*)(x + (long)t * 1024))[tid];
    float s = v.x + v.y + v.z + v.w;
    float q = v.x * v.x + v.y * v.y + v.z * v.z + v.w * v.w;
    for (int o = 32; o > 0; o >>= 1) { s += __shfl_xor(s, o, 64); q += __shfl_xor(q, o, 64); }
    __shared__ float ss[4], sq[4];
    const int wave = tid >> 6, lane = tid & 63;
    if (lane == 0) { ss[wave] = s; sq[wave] = q; }
    __syncthreads();
    s = ss[0] + ss[1] + ss[2] + ss[3];
    q = sq[0] + sq[1] + sq[2] + sq[3];
    const float mean = s * (1.0f / 1024.0f);
    const float var = q * (1.0f / 1024.0f) - mean * mean;
    const float rstd = 1.0f / sqrtf(var + 1e-5f);
    const long row = (long)t + 2 + 4 * (t >> 12);
    UST* ph = oh + row * 1024 + tid * 4;
    UST* pl = ol + row * 1024 + tid * 4;
    const float4 gg = ((const float4*)g)[tid];
    const float4 bb = ((const float4*)b)[tid];
    float vv[4] = { v.x, v.y, v.z, v.w };
    float gv[4] = { gg.x, gg.y, gg.z, gg.w };
    float bv[4] = { bb.x, bb.y, bb.z, bb.w };
#pragma unroll
    for (int j = 0; j < 4; j++) {
        float f = (vv[j] - mean) * rstd * gv[j] + bv[j];
        UST hi = f2bf(f);
        ph[j] = hi;
        pl[j] = f2bf(f - bf2f(hi));
    }
}

// zero the conv-pad rows {b*4100 + 0,1,4098,4099} of LNh/LNl
__global__ void ln_pad_kernel(UST* __restrict__ oh, UST* __restrict__ ol)
{
    const int blk = blockIdx.x;          // 8 blocks
    const int b = blk >> 2, rsel = blk & 3;
    const long row = (long)b * 4100 + (rsel < 2 ? rsel : 4096 + rsel);
    const int tid = threadIdx.x;
    *(ushort4*)(oh + row * 1024 + tid * 4) = make_ushort4(0, 0, 0, 0);
    *(ushort4*)(ol + row * 1024 + tid * 4) = make_ushort4(0, 0, 0, 0);
}

// ---------------------------------------------------------------------------
// Coalesced transpose prep: dst[n*K+k] = src[k*N+n], bf16 hi (+lo).
// ---------------------------------------------------------------------------
__global__ void prep_t_kernel(const float* __restrict__ src, UST* __restrict__ dh,
                              UST* __restrict__ dl, int N, int K)
{
    __shared__ float tile[32][65];
    const int k0 = blockIdx.y * 32, n0 = blockIdx.x * 64;
    const int t = threadIdx.x;
    const int nn = t & 63, kk = t >> 6;
#pragma unroll
    for (int i = 0; i < 8; i++)
        tile[kk + i * 4][nn] = src[(long)(k0 + kk + i * 4) * N + n0 + nn];
    __syncthreads();
    const int kw = (t & 7) * 4;
#pragma unroll
    for (int pass = 0; pass < 2; pass++) {
        const int nw = (t >> 3) + pass * 32;
        UST hv[4], lv[4];
#pragma unroll
        for (int j = 0; j < 4; j++) {
            float v = tile[kw + j][nw];
            hv[j] = f2bf(v);
            lv[j] = f2bf(v - bf2f(hv[j]));
        }
        UST* bh = dh + (long)(n0 + nw) * K + k0 + kw;
        *(ushort4*)bh = make_ushort4(hv[0], hv[1], hv[2], hv[3]);
        if (dl) {
            UST* bl = dl + (long)(n0 + nw) * K + k0 + kw;
            *(ushort4*)bl = make_ushort4(lv[0], lv[1], lv[2], lv[3]);
        }
    }
}

// conv taps into concatenated B: dst[n*dstK + dstOff + k] = src[k*sr + n*sc]
__global__ void prep_w_kernel(const float* __restrict__ src, UST* __restrict__ dh,
                              UST* __restrict__ dl, int K, long sr, long sc,
                              int dstK, int dstOff, long total)
{
    long gid = (long)blockIdx.x * 256 + threadIdx.x;
    if (gid >= total) return;
    long n = gid / K, k = gid - n * K;
    float v = src[k * sr + n * sc];
    UST hi = f2bf(v);
    long di = n * dstK + dstOff + k;
    dh[di] = hi;
    if (dl) dl[di] = f2bf(v - bf2f(hi));
}

// ---------------------------------------------------------------------------
// GEMM: C[M,N] = A[M,K] * B^T[N,K]  (bf16, fp32 accum, MFMA 16x16x32)
// 128x128 tile, BK=32, 256 threads, global_load_lds(16B) staging.
// SPLIT: A=Ah+Al, B=Bh+Bl -> AhBh + AhBl + AlBh (fp32-grade).
// A row stride KA; A k-offset = k0 + (k0>>10)*ASHIFT (conv seg trick: segment
// s reads +2048 elements = +2 rows -> tap s hits row t+2s).
// EPI 0: Cf = acc(+bias)(+resid) fp32. EPI 1: Cb = bf16(gelu(acc+bias)).
// EPI 2: scatter split bf16 into Sp = [Qh|Ql|Kh|Kl|Vth|Vtl] (attention prep).
// ---------------------------------------------------------------------------
template<int EPI, bool SPLIT, int ASHIFT>
__global__ __launch_bounds__(256)
void gemm_bt_kernel(const UST* __restrict__ Ah, const UST* __restrict__ Al,
                    const UST* __restrict__ Bh, const UST* __restrict__ Bl,
                    const float* __restrict__ bias, const float* __restrict__ resid,
                    float* __restrict__ Cf, UST* __restrict__ Cb, UST* __restrict__ Sp,
                    int M, int N, int K, int KA, int rb, int radd)
{
    __shared__ UST sA[(SPLIT ? 2 : 1) * 128 * 32];
    __shared__ UST sB[(SPLIT ? 2 : 1) * 128 * 32];
    const int tid = threadIdx.x;
    const int lane = tid & 63;
    const int wv = __builtin_amdgcn_readfirstlane(tid >> 6);
    const int wr = wv >> 1, wc = wv & 1;
    const int lm = lane & 15, lq = lane >> 4;
    const long m0 = (long)blockIdx.y * 128, n0 = (long)blockIdx.x * 128;

    const int lr = lane >> 2, lc = (lane & 3) * 8;
    const int rA0 = wv * 32 + lr, rA1 = wv * 32 + 16 + lr;
    const long mtop = m0 >> 12;              // tiles never straddle 4096 rows
    const UST* gA0 = Ah + (m0 + rA0 + rb + (long)radd * mtop) * KA + lc;
    const UST* gA1 = Ah + (m0 + rA1 + rb + (long)radd * mtop) * KA + lc;
    const UST* gB0 = Bh + (n0 + rA0) * K + lc;
    const UST* gB1 = Bh + (n0 + rA1) * K + lc;
    const UST* gA0l = SPLIT ? (Al + (m0 + rA0 + rb + (long)radd * mtop) * KA + lc) : nullptr;
    const UST* gA1l = SPLIT ? (Al + (m0 + rA1 + rb + (long)radd * mtop) * KA + lc) : nullptr;
    const UST* gB0l = SPLIT ? (Bl + (n0 + rA0) * K + lc) : nullptr;
    const UST* gB1l = SPLIT ? (Bl + (n0 + rA1) * K + lc) : nullptr;
    UST* lA0 = &sA[wv * 1024];               // wave-uniform LDS bases
    UST* lA1 = &sA[wv * 1024 + 512];
    UST* lB0 = &sB[wv * 1024];
    UST* lB1 = &sB[wv * 1024 + 512];

    f32x4 acc[4][4] = {};

    for (int k0 = 0; k0 < K; k0 += 32) {
        const long aoff = ASHIFT ? (long)k0 + (long)(k0 >> 10) * ASHIFT : (long)k0;
        GLL(gA0 + aoff, lA0); GLL(gA1 + aoff, lA1);
        GLL(gB0 + k0, lB0); GLL(gB1 + k0, lB1);
        if (SPLIT) {
            GLL(gA0l + aoff, lA0 + 4096); GLL(gA1l + aoff, lA1 + 4096);
            GLL(gB0l + k0, lB0 + 4096); GLL(gB1l + k0, lB1 + 4096);
        }
        __syncthreads();
        s16x8 ah[4], bh[4];
#pragma unroll
        for (int i = 0; i < 4; i++) {
            ah[i] = *(const s16x8*)&sA[(wr * 64 + i * 16 + lm) * 32 + lq * 8];
            bh[i] = *(const s16x8*)&sB[(wc * 64 + i * 16 + lm) * 32 + lq * 8];
        }
#pragma unroll
        for (int i = 0; i < 4; i++)
#pragma unroll
            for (int j = 0; j < 4; j++)
                acc[i][j] = MFMA16(ah[i], bh[j], acc[i][j], 0, 0, 0);
        if (SPLIT) {
            s16x8 al[4], bl[4];
#pragma unroll
            for (int i = 0; i < 4; i++) {
                al[i] = *(const s16x8*)&sA[4096 + (wr * 64 + i * 16 + lm) * 32 + lq * 8];
                bl[i] = *(const s16x8*)&sB[4096 + (wc * 64 + i * 16 + lm) * 32 + lq * 8];
            }
#pragma unroll
            for (int i = 0; i < 4; i++)
#pragma unroll
                for (int j = 0; j < 4; j++) {
                    acc[i][j] = MFMA16(ah[i], bl[j], acc[i][j], 0, 0, 0);
                    acc[i][j] = MFMA16(al[i], bh[j], acc[i][j], 0, 0, 0);
                }
        }
        __syncthreads();
    }

    // C/D layout (m89/m91-verified): col = lane&15, row = (lane>>4)*4 + reg
    const long SZ = 8388608L;
    const int colbase = (int)n0 + wc * 64;          // wave-uniform
    const int part = colbase >> 10;                 // EPI2: 0=Q,1=K,2=V
    const int hh = (colbase & 1023) >> 6;
    UST* H = (EPI == 2) ? (Sp + (long)part * 2 * SZ) : nullptr;
    UST* Lo = (EPI == 2) ? (H + SZ) : nullptr;
#pragma unroll
    for (int i = 0; i < 4; i++) {
#pragma unroll
        for (int j = 0; j < 4; j++) {
#pragma unroll
            for (int r = 0; r < 4; r++) {
                const long grow = m0 + wr * 64 + i * 16 + lq * 4 + r;
                const long gcol = n0 + wc * 64 + j * 16 + lm;
                float v = acc[i][j][r];
                if (bias) v += bias[gcol];
                if (EPI == 0) {
                    const long idx = grow * N + gcol;
                    if (resid) v += resid[idx];
                    Cf[idx] = v;
                } else if (EPI == 1) {
                    Cb[grow * N + gcol] = f2bf(gelu_f(v));
                } else {
                    const int d = j * 16 + lm;      // col within head
                    long idx;
                    if (part < 2) {
                        idx = ((long)hh * 8192 + grow) * 64 + d;
                    } else {
                        const int bb = (int)(grow >> 12), ww = (int)((grow >> 8) & 15),
                                  tt = (int)(grow & 255);
                        idx = ((long)((bb * 16 + ww) * 16 + hh)) * 16384 + (long)d * 256 + tt;
                    }
                    UST hi = f2bf(v);
                    H[idx] = hi;
                    Lo[idx] = f2bf(v - bf2f(hi));
                }
            }
        }
    }
}

// ---------------------------------------------------------------------------
// MFMA windowed attention (split-bf16, fp32-grade). Block = (b,win,head),
// 4 waves; wave owns 64 q-rows, iterates 8 k-chunks of 32 keys.
// S = QhKh+QhKl+QlKh (fp32 acc) -> P = exp(S/8) fp32 (scores bounded, no max)
// -> P split hi/lo through per-wave LDS (stride 40, 16B-aligned frag reads)
// -> O += PhVh+PhVl+PlVh.  l accumulated via cross-lane xor-reduce.
// Q frags live in registers whole kernel; K/V frags read from global (L2).
// ---------------------------------------------------------------------------
__global__ __launch_bounds__(256, 2)
void attn_mfma_kernel(const UST* __restrict__ Sp, UST* __restrict__ oh, UST* __restrict__ ol)
{
    __shared__ UST sPh[4 * 64 * 40];
    __shared__ UST sPl[4 * 64 * 40];
    const long SZ = 8388608L;
    const UST* Qh = Sp;
    const UST* Ql = Sp + SZ;
    const UST* Kh = Sp + 2 * SZ;
    const UST* Kl = Sp + 3 * SZ;
    const UST* Vth = Sp + 4 * SZ;
    const UST* Vtl = Sp + 5 * SZ;
    const int blk = blockIdx.x;
    const int h = blk & 15, w = (blk >> 4) & 15, b = blk >> 8;
    const long tok0 = (long)b * 4096 + w * 256;
    const int tid = threadIdx.x;
    const int lane = tid & 63;
    const int wv = tid >> 6;
    const int lm = lane & 15, lq = lane >> 4;

    // Q fragments (A-operand: m=lane&15, k=(lane>>4)*8+j), resident all kernel
    const long qrow0 = (long)h * 8192 + tok0 + wv * 64;
    s16x8 qhf[4][2], qlf[4][2];
#pragma unroll
    for (int mt = 0; mt < 4; mt++)
#pragma unroll
        for (int ks = 0; ks < 2; ks++) {
            const long o = (qrow0 + mt * 16 + lm) * 64 + ks * 32 + lq * 8;
            qhf[mt][ks] = *(const s16x8*)(Qh + o);
            qlf[mt][ks] = *(const s16x8*)(Ql + o);
        }
    const long krow0 = (long)h * 8192 + tok0;
    const long vbase = (long)blk * 16384;

    f32x4 Oacc[4][4] = {};
    float lsum[4][4] = {};
    UST* myPh = &sPh[wv * 2560];
    UST* myPl = &sPl[wv * 2560];

    for (int c = 0; c < 8; c++) {
        const int kt = c * 32;
        // ---- S = Q K^T (64q x 32k), split 3-product ----
        f32x4 S[4][2] = {};
#pragma unroll
        for (int nt = 0; nt < 2; nt++)
#pragma unroll
            for (int ks = 0; ks < 2; ks++) {
                const long o = (krow0 + kt + nt * 16 + lm) * 64 + ks * 32 + lq * 8;
                s16x8 khf = *(const s16x8*)(Kh + o);
                s16x8 klf = *(const s16x8*)(Kl + o);
#pragma unroll
                for (int mt = 0; mt < 4; mt++) {
                    S[mt][nt] = MFMA16(qhf[mt][ks], khf, S[mt][nt], 0, 0, 0);
                    S[mt][nt] = MFMA16(qhf[mt][ks], klf, S[mt][nt], 0, 0, 0);
                    S[mt][nt] = MFMA16(qlf[mt][ks], khf, S[mt][nt], 0, 0, 0);
                }
            }
        // ---- P = exp(S/8); l partial; write P split to LDS ----
#pragma unroll
        for (int mt = 0; mt < 4; mt++)
#pragma unroll
            for (int r = 0; r < 4; r++) {
                float p0 = __expf(S[mt][0][r] * 0.125f);
                float p1 = __expf(S[mt][1][r] * 0.125f);
                float part = p0 + p1;
                part += __shfl_xor(part, 1, 64);
                part += __shfl_xor(part, 2, 64);
                part += __shfl_xor(part, 4, 64);
                part += __shfl_xor(part, 8, 64);
                lsum[mt][r] += part;
                const int q = mt * 16 + lq * 4 + r;
                UST h0 = f2bf(p0), h1 = f2bf(p1);
                myPh[q * 40 + lm] = h0;
                myPh[q * 40 + 16 + lm] = h1;
                myPl[q * 40 + lm] = f2bf(p0 - bf2f(h0));
                myPl[q * 40 + 16 + lm] = f2bf(p1 - bf2f(h1));
            }
        // ---- O += P V (P from LDS A-frags, V^T from global B-frags) ----
#pragma unroll
        for (int mt = 0; mt < 4; mt++) {
            s16x8 phf = *(const s16x8*)(myPh + (mt * 16 + lm) * 40 + lq * 8);
            s16x8 plf = *(const s16x8*)(myPl + (mt * 16 + lm) * 40 + lq * 8);
#pragma unroll
            for (int dt = 0; dt < 4; dt++) {
                const long o = vbase + (dt * 16 + lm) * 256 + kt + lq * 8;
                s16x8 vhf = *(const s16x8*)(Vth + o);
                s16x8 vlf = *(const s16x8*)(Vtl + o);
                Oacc[mt][dt] = MFMA16(phf, vhf, Oacc[mt][dt], 0, 0, 0);
                Oacc[mt][dt] = MFMA16(phf, vlf, Oacc[mt][dt], 0, 0, 0);
                Oacc[mt][dt] = MFMA16(plf, vhf, Oacc[mt][dt], 0, 0, 0);
            }
        }
    }
    // ---- normalize + write split bf16 ----
#pragma unroll
    for (int mt = 0; mt < 4; mt++)
#pragma unroll
        for (int r = 0; r < 4; r++) {
            const float inv = 1.0f / lsum[mt][r];
            const long tok = tok0 + wv * 64 + mt * 16 + lq * 4 + r;
            UST* po = oh + tok * 1024 + h * 64;
            UST* plo = ol + tok * 1024 + h * 64;
#pragma unroll
            for (int dt = 0; dt < 4; dt++) {
                float f = Oacc[mt][dt][r] * inv;
                UST hv = f2bf(f);
                po[dt * 16 + lm] = hv;
                plo[dt * 16 + lm] = f2bf(f - bf2f(hv));
            }
        }
}

// ---------------------------------------------------------------------------
// Gate: logits (hi+lo fp32-grade), softmax, entropy, top-2 -> combine weights.
// ---------------------------------------------------------------------------
__global__ void gate_kernel(const UST* __restrict__ lnh, const UST* __restrict__ lnl,
                            const float* __restrict__ gw, const float* __restrict__ gb,
                            float* __restrict__ combine, float* __restrict__ ent_acc)
{
    const int tid = threadIdx.x;
    const int t = blockIdx.x * 4 + (tid >> 6);
    const int lane = tid & 63;
    const long row = (long)t + 2 + 4 * (t >> 12);
    const UST* ph = lnh + row * 1024;
    const UST* pl = lnl + row * 1024;
    float acc[8] = { 0, 0, 0, 0, 0, 0, 0, 0 };
    for (int c = 0; c < 16; c++) {
        int d = c * 64 + lane;
        float xv = bf2f(ph[d]) + bf2f(pl[d]);
        const float* wr = gw + (long)d * 8;
#pragma unroll
        for (int e = 0; e < 8; e++) acc[e] += xv * wr[e];
    }
#pragma unroll
    for (int e = 0; e < 8; e++)
        for (int o = 32; o > 0; o >>= 1) acc[e] += __shfl_xor(acc[e], o, 64);
    if (lane == 0) {
        float lg[8], p[8];
        float mx = -1e30f;
        for (int e = 0; e < 8; e++) { lg[e] = acc[e] + gb[e]; mx = fmaxf(mx, lg[e]); }
        float sum = 0;
        for (int e = 0; e < 8; e++) { p[e] = expf(lg[e] - mx); sum += p[e]; }
        float inv = 1.0f / sum;
        float ent = 0;
        for (int e = 0; e < 8; e++) { p[e] *= inv; ent -= p[e] * logf(p[e] + 1e-10f); }
        int i1 = 0; float v1 = -1e30f;
        for (int e = 0; e < 8; e++) if (p[e] > v1) { v1 = p[e]; i1 = e; }
        int i2 = 0; float v2 = -1e30f;
        for (int e = 0; e < 8; e++) if (e != i1 && p[e] > v2) { v2 = p[e]; i2 = e; }
        float inv2 = 1.0f / (v1 + v2);
        float cw[8] = { 0, 0, 0, 0, 0, 0, 0, 0 };
        cw[i1] = v1 * inv2; cw[i2] = v2 * inv2;
        float* co = combine + (long)t * 8;
        for (int e = 0; e < 8; e++) co[e] = cw[e];
        atomicAdd(ent_acc, ent);
    }
}

// out[t,f] += sum_j combine[t, half*4+j] * y[t, j*1024+f]
__global__ void moe_combine_kernel(const UST* __restrict__ y, const float* __restrict__ combine,
                                   float* __restrict__ out, int halfsel)
{
    const long gid = (long)blockIdx.x * 256 + threadIdx.x;
    const int t = (int)(gid >> 10), f = (int)(gid & 1023);
    const float* cw = combine + (long)t * 8 + halfsel * 4;
    const UST* yp = y + (long)t * 4096 + f;
    float s = cw[0] * bf2f(yp[0]) + cw[1] * bf2f(yp[1024])
            + cw[2] * bf2f(yp[2048]) + cw[3] * bf2f(yp[3072]);
    out[gid] += s;
}

__global__ void f32_to_bf16_kernel(const float* __restrict__ in, UST* __restrict__ out)
{
    long gid = ((long)blockIdx.x * 256 + threadIdx.x) * 4;
    float4 v = *(const float4*)(in + gid);
    out[gid] = f2bf(v.x); out[gid + 1] = f2bf(v.y);
    out[gid + 2] = f2bf(v.z); out[gid + 3] = f2bf(v.w);
}

__global__ void ent_final_kernel(const float* __restrict__ acc, float* __restrict__ out)
{
    out[0] = 0.1f * acc[0] * (1.0f / 8192.0f);
}

// ===========================================================================
extern "C" void kernel_launch(void* const* d_in, const int* in_sizes, int n_in,
                              void* d_out_, int out_size, void* d_ws, size_t ws_size,
                              hipStream_t stream)
{
    const float* x      = (const float*)d_in[0];
    const float* ln1_g  = (const float*)d_in[1];
    const float* ln1_b  = (const float*)d_in[2];
    const float* qkv_w  = (const float*)d_in[3];
    const float* qkv_b  = (const float*)d_in[4];
    const float* ao_w   = (const float*)d_in[5];
    const float* ao_b   = (const float*)d_in[6];
    const float* ln2_g  = (const float*)d_in[7];
    const float* ln2_b  = (const float*)d_in[8];
    const float* conv_w = (const float*)d_in[9];
    const float* conv_b = (const float*)d_in[10];
    const float* ln3_g  = (const float*)d_in[11];
    const float* ln3_b  = (const float*)d_in[12];
    const float* gate_w = (const float*)d_in[13];
    const float* gate_b = (const float*)d_in[14];
    const float* exp_w  = (const float*)d_in[15];
    const float* exp_b  = (const float*)d_in[16];
    const float* ff_w1  = (const float*)d_in[17];
    const float* ff_b1  = (const float*)d_in[18];
    const float* ff_w2  = (const float*)d_in[19];
    const float* ff_b2  = (const float*)d_in[20];
    float* out = (float*)d_out_;

    char* ws = (char*)d_ws;
    size_t off = 0;
    auto alloc = [&](size_t bytes) -> char* {
        char* p = ws + off;
        off += (bytes + 255) & ~(size_t)255;
        return p;
    };
    UST* qkvWh = (UST*)alloc(3072 * 1024 * 2);
    UST* qkvWl = (UST*)alloc(3072 * 1024 * 2);
    UST* aoWh  = (UST*)alloc(1024 * 1024 * 2);
    UST* aoWl  = (UST*)alloc(1024 * 1024 * 2);
    UST* convCh = (UST*)alloc(1024L * 3072 * 2);   // [n=1024][k=3072] concat taps
    UST* convCl = (UST*)alloc(1024L * 3072 * 2);
    UST* expW  = (UST*)alloc(8192L * 1024 * 2);
    UST* ff1W  = (UST*)alloc(4096L * 1024 * 2);
    UST* ff2W  = (UST*)alloc(4096L * 1024 * 2);
    const size_t LN_BYTES = 8200L * 1024 * 2;
    UST* LNh = (UST*)alloc(LN_BYTES);
    UST* LNl = (UST*)alloc(LN_BYTES);
    float* combine = (float*)alloc(8192 * 8 * 4);
    float* entacc  = (float*)alloc(256);
    char*  BIG = alloc(8192L * 3072 * 4);     // Sp (6x16MB) during attn; y/h1 later
    UST* OH = (UST*)alloc(8192L * 1024 * 2);  // attn out hi; later x3 bf16
    UST* OL = (UST*)alloc(8192L * 1024 * 2);
    if (off > ws_size) return;  // ws too small -> deliberate clean fail

    UST* Sp   = (UST*)BIG;      // [Qh|Ql|Kh|Kl|Vth|Vtl]
    UST* ybuf = (UST*)BIG;
    UST* h1   = (UST*)BIG;
    UST* x3h  = OH;

    // ---- weight prep (every call; ws is re-poisoned) ----
    auto nb = [](long n) { return (unsigned)((n + 255) / 256); };
    prep_t_kernel<<<dim3(48, 32), 256, 0, stream>>>(qkv_w, qkvWh, qkvWl, 3072, 1024);
    prep_t_kernel<<<dim3(16, 32), 256, 0, stream>>>(ao_w, aoWh, aoWl, 1024, 1024);
    for (int k = 0; k < 3; k++)
        prep_w_kernel<<<nb(1024L * 1024), 256, 0, stream>>>(conv_w + k, convCh, convCl,
                                                            1024, 3, 3072, 3072, k * 1024, 1024L * 1024);
    for (int e = 0; e < 8; e++)
        prep_t_kernel<<<dim3(16, 32), 256, 0, stream>>>(exp_w + (long)e * 1048576, expW + (long)e * 1048576,
                                                        nullptr, 1024, 1024);
    prep_t_kernel<<<dim3(64, 32), 256, 0, stream>>>(ff_w1, ff1W, nullptr, 4096, 1024);
    prep_t_kernel<<<dim3(16, 128), 256, 0, stream>>>(ff_w2, ff2W, nullptr, 1024, 4096);

    ln_pad_kernel<<<8, 256, 0, stream>>>(LNh, LNl);
    hipMemsetAsync(entacc, 0, 4, stream);

    // ---- attention block ----
    ln_split_kernel<<<8192, 256, 0, stream>>>(x, ln1_g, ln1_b, LNh, LNl);
    gemm_bt_kernel<2, true, 0><<<dim3(24, 64), 256, 0, stream>>>(LNh, LNl, qkvWh, qkvWl, qkv_b, nullptr,
                                                                 nullptr, nullptr, Sp, 8192, 3072, 1024, 1024, 2, 4);
    attn_mfma_kernel<<<512, 256, 0, stream>>>(Sp, OH, OL);
    gemm_bt_kernel<0, true, 0><<<dim3(8, 64), 256, 0, stream>>>(OH, OL, aoWh, aoWl, ao_b, x,
                                                                out, nullptr, nullptr, 8192, 1024, 1024, 1024, 0, 0);
    // ---- dilated conv block: ONE fused GEMM, K=3072 (3 shifted segments) ----
    ln_split_kernel<<<8192, 256, 0, stream>>>(out, ln2_g, ln2_b, LNh, LNl);
    gemm_bt_kernel<0, true, 1024><<<dim3(8, 64), 256, 0, stream>>>(LNh, LNl, convCh, convCl, conv_b, out,
                                                                   out, nullptr, nullptr, 8192, 1024, 3072, 1024, 0, 4);
    // ---- MoE ----
    ln_split_kernel<<<8192, 256, 0, stream>>>(out, ln3_g, ln3_b, LNh, LNl);
    gate_kernel<<<2048, 256, 0, stream>>>(LNh, LNl, gate_w, gate_b, combine, entacc);
    ent_final_kernel<<<1, 1, 0, stream>>>(entacc, out + 8388608);
    for (int hh = 0; hh < 2; hh++) {
        gemm_bt_kernel<1, false, 0><<<dim3(32, 64), 256, 0, stream>>>(LNh, nullptr, expW + (long)hh * 4096 * 1024,
                                                                      nullptr, exp_b + hh * 4096, nullptr,
                                                                      nullptr, ybuf, nullptr, 8192, 4096, 1024, 1024, 2, 4);
        moe_combine_kernel<<<32768, 256, 0, stream>>>(ybuf, combine, out, hh);
    }
    // ---- FFN ----
    f32_to_bf16_kernel<<<8192, 256, 0, stream>>>(out, x3h);
    gemm_bt_kernel<1, false, 0><<<dim3(32, 64), 256, 0, stream>>>(x3h, nullptr, ff1W, nullptr, ff_b1, nullptr,
                                                                  nullptr, h1, nullptr, 8192, 4096, 1024, 1024, 0, 0);
    gemm_bt_kernel<0, false, 0><<<dim3(8, 64), 256, 0, stream>>>(h1, nullptr, ff2W, nullptr, ff_b2, out,
                                                                 out, nullptr, nullptr, 8192, 1024, 4096, 4096, 0, 0);
}